// Round 1
// 368.944 us; speedup vs baseline: 1.3298x; 1.3298x over previous
//
#include <hip/hip_runtime.h>
#include <math.h>

#define CHUNK 32
#define DK 128
#define DV 128
#define L_SEQ 4096
#define BH 32
#define NCH 128

typedef __attribute__((ext_vector_type(8))) short bf16x8;
typedef __attribute__((ext_vector_type(4))) float f32x4;

union U8 { unsigned int u[4]; bf16x8 v; };

#define MFMA16(a, b, c) __builtin_amdgcn_mfma_f32_16x16x32_bf16((a), (b), (c), 0, 0, 0)
#define LGKM_WAIT() __asm__ __volatile__("s_waitcnt lgkmcnt(0)" ::: "memory")

__device__ __forceinline__ unsigned short f2bf(float x){
    unsigned int u = __builtin_bit_cast(unsigned int, x);
    u = u + 0x7FFFu + ((u >> 16) & 1u);   // RNE
    return (unsigned short)(u >> 16);
}
// RNE pack of two f32 -> packed bf16 pair. Single HW instruction (identical
// rounding to the manual +0x7FFF+odd path, ~9x fewer VALU ops).
__device__ __forceinline__ unsigned int pk2(float a, float b){
    unsigned int r;
    asm("v_cvt_pk_bf16_f32 %0, %1, %2" : "=v"(r) : "v"(a), "v"(b));
    return r;
}

__device__ __forceinline__ bf16x8 afragF32(const float (*M)[36], int row, int q8){
    float4 f0 = *(const float4*)&M[row][q8];
    float4 f1 = *(const float4*)&M[row][q8 + 4];
    U8 t;
    t.u[0] = pk2(f0.x, f0.y); t.u[1] = pk2(f0.z, f0.w);
    t.u[2] = pk2(f1.x, f1.y); t.u[3] = pk2(f1.z, f1.w);
    return t.v;
}
__device__ __forceinline__ bf16x8 bfragF32(const float (*M)[36], int q8, int col){
    U8 t;
#pragma unroll
    for (int j2 = 0; j2 < 4; ++j2)
        t.u[j2] = pk2(M[q8 + 2*j2][col], M[q8 + 2*j2 + 1][col]);
    return t.v;
}

// ---------------- Phase 1: fully parallel per-chunk prep (MFMA) ------------
// One 64-thread block per (bh,chunk). Outputs to ws:
//   qw/kw : bf16, L2-normalized q/k rows  [bh][L][128]
//   Tw    : bf16 T = (I+A)^{-1}           [bh][nch][32][32]
//   Aw    : bf16 attn = tril(qn kn^T)     [bh][nch][32][32]

__global__ __launch_bounds__(64, 1)
void prep_kernel(const float* __restrict__ q, const float* __restrict__ k,
                 const float* __restrict__ beta,
                 unsigned short* __restrict__ qw, unsigned short* __restrict__ kw,
                 unsigned short* __restrict__ Tw, unsigned short* __restrict__ Aw)
{
    const int bc = blockIdx.x;               // bh*NCH + ch
    const size_t row0 = (size_t)bc * CHUNK;
    const int l = threadIdx.x;
    const int r = l & 31, h = l >> 5;
    const int quad = (l >> 4) & 3, ln15 = l & 15, q8 = quad * 8;

    __shared__ unsigned short qn_s[32][136], kn_s[32][136], kb_s[32][136];
    __shared__ float Ms[32][36];
    __shared__ float Rs[32][36];

    const float bet = beta[row0 + r];

    // ---- load q row-half, normalize, cvt, stage + store ----
    {
        const float4* gp = (const float4*)(q + (row0 + r) * DK + 64 * h);
        float vb[64]; float s = 0.f;
#pragma unroll
        for (int e = 0; e < 16; ++e){
            float4 a = gp[e];
            vb[4*e+0]=a.x; vb[4*e+1]=a.y; vb[4*e+2]=a.z; vb[4*e+3]=a.w;
            s += a.x*a.x + a.y*a.y + a.z*a.z + a.w*a.w;
        }
        s += __shfl_xor(s, 32);
        float sc = rsqrtf(s + 1e-6f);
#pragma unroll
        for (int e = 0; e < 8; ++e){
            U8 t;
#pragma unroll
            for (int j = 0; j < 4; ++j)
                t.u[j] = pk2(vb[8*e+2*j] * sc, vb[8*e+2*j+1] * sc);
            *(bf16x8*)&qn_s[r][64*h + 8*e] = t.v;
            *(bf16x8*)(qw + (row0 + r) * DK + 64*h + 8*e) = t.v;
        }
    }
    // ---- k: kn + kb = kn*beta ----
    {
        const float4* gp = (const float4*)(k + (row0 + r) * DK + 64 * h);
        float vb[64]; float s = 0.f;
#pragma unroll
        for (int e = 0; e < 16; ++e){
            float4 a = gp[e];
            vb[4*e+0]=a.x; vb[4*e+1]=a.y; vb[4*e+2]=a.z; vb[4*e+3]=a.w;
            s += a.x*a.x + a.y*a.y + a.z*a.z + a.w*a.w;
        }
        s += __shfl_xor(s, 32);
        float sc = rsqrtf(s + 1e-6f);
#pragma unroll
        for (int e = 0; e < 8; ++e){
            U8 t, tb;
#pragma unroll
            for (int j = 0; j < 4; ++j){
                float x0 = vb[8*e+2*j] * sc, x1 = vb[8*e+2*j+1] * sc;
                t.u[j]  = pk2(x0, x1);
                tb.u[j] = pk2(x0 * bet, x1 * bet);
            }
            *(bf16x8*)&kn_s[r][64*h + 8*e] = t.v;
            *(bf16x8*)&kb_s[r][64*h + 8*e] = tb.v;
            *(bf16x8*)(kw + (row0 + r) * DK + 64*h + 8*e) = t.v;
        }
    }
    LGKM_WAIT();

    // ---- B = kb @ kn^T ; attn = qn @ kn^T  (MFMA, K=128) ----
    f32x4 Z = {0.f, 0.f, 0.f, 0.f};
    f32x4 Bacc[2][2] = {{Z, Z}, {Z, Z}};
    f32x4 Aacc[2][2] = {{Z, Z}, {Z, Z}};
#pragma unroll
    for (int ks = 0; ks < 4; ++ks){
        bf16x8 bF[2];
        bF[0] = *(const bf16x8*)&kn_s[ln15][32*ks + q8];
        bF[1] = *(const bf16x8*)&kn_s[16 + ln15][32*ks + q8];
#pragma unroll
        for (int mt = 0; mt < 2; ++mt){
            bf16x8 aK = *(const bf16x8*)&kb_s[16*mt + ln15][32*ks + q8];
            bf16x8 aQ = *(const bf16x8*)&qn_s[16*mt + ln15][32*ks + q8];
#pragma unroll
            for (int nt = 0; nt < 2; ++nt){
                Bacc[mt][nt] = MFMA16(aK, bF[nt], Bacc[mt][nt]);
                Aacc[mt][nt] = MFMA16(aQ, bF[nt], Aacc[mt][nt]);
            }
        }
    }

    // ---- masks; store attn; stage B; init R = I + B ----
    f32x4 Rc[2][2];
#pragma unroll
    for (int mt = 0; mt < 2; ++mt)
#pragma unroll
    for (int nt = 0; nt < 2; ++nt)
#pragma unroll
    for (int rg = 0; rg < 4; ++rg){
        int row = 16*mt + 4*quad + rg, col = 16*nt + ln15;
        float av = (col <= row) ? Aacc[mt][nt][rg] : 0.f;
        Aw[((size_t)bc << 10) + row*32 + col] = f2bf(av);
        float bm = (col < row) ? -Bacc[mt][nt][rg] : 0.f;
        Ms[row][col] = bm;
        Rc[mt][nt][rg] = bm + ((col == row) ? 1.f : 0.f);
    }

    // ---- doubling: R <- R(I+B^2)(I+B^4)(I+B^8)(I+B^16) ----
#pragma unroll 1
    for (int rd = 0; rd < 4; ++rd){
        LGKM_WAIT();
        bf16x8 Am[2], Bm2[2];
#pragma unroll
        for (int mt = 0; mt < 2; ++mt) Am[mt] = afragF32(Ms, 16*mt + ln15, q8);
#pragma unroll
        for (int nt = 0; nt < 2; ++nt) Bm2[nt] = bfragF32(Ms, q8, 16*nt + ln15);
        f32x4 Mq[2][2];
#pragma unroll
        for (int mt = 0; mt < 2; ++mt)
#pragma unroll
        for (int nt = 0; nt < 2; ++nt)
            Mq[mt][nt] = MFMA16(Am[mt], Bm2[nt], Z);
        // stage R and M^2
#pragma unroll
        for (int mt = 0; mt < 2; ++mt)
#pragma unroll
        for (int nt = 0; nt < 2; ++nt)
#pragma unroll
        for (int rg = 0; rg < 4; ++rg){
            int row = 16*mt + 4*quad + rg, col = 16*nt + ln15;
            Rs[row][col] = Rc[mt][nt][rg];
            Ms[row][col] = Mq[mt][nt][rg];
        }
        LGKM_WAIT();
        bf16x8 Ar[2], Bq[2];
#pragma unroll
        for (int mt = 0; mt < 2; ++mt) Ar[mt] = afragF32(Rs, 16*mt + ln15, q8);
#pragma unroll
        for (int nt = 0; nt < 2; ++nt) Bq[nt] = bfragF32(Ms, q8, 16*nt + ln15);
#pragma unroll
        for (int mt = 0; mt < 2; ++mt)
#pragma unroll
        for (int nt = 0; nt < 2; ++nt)
            Rc[mt][nt] = MFMA16(Ar[mt], Bq[nt], Rc[mt][nt]);   // R += R~ * M^2
    }

    // ---- store T ----
#pragma unroll
    for (int mt = 0; mt < 2; ++mt)
#pragma unroll
    for (int nt = 0; nt < 2; ++nt)
#pragma unroll
    for (int rg = 0; rg < 4; ++rg){
        int row = 16*mt + 4*quad + rg, col = 16*nt + ln15;
        Tw[((size_t)bc << 10) + row*32 + col] = f2bf(Rc[mt][nt][rg]);
    }
}

// ---------------- Phase 2: sequential scan — 1 wave/block, no barriers -----
// grid 256: id = bh + 32*cb (8 col-siblings of a bh land on one XCD).
// Rotated-body schedule: no explicit lgkm drains (compiler counted waits),
// knT gather split into the Xt/ut round-trip shadows, all per-chunk global
// operands prefetched one full body ahead.

__global__ __launch_bounds__(64, 1)
void scan_kernel(const float* __restrict__ v, const float* __restrict__ beta,
                 const unsigned short* __restrict__ qw, const unsigned short* __restrict__ kw,
                 const unsigned short* __restrict__ Tw, const unsigned short* __restrict__ Aw,
                 float* __restrict__ out)
{
    const int id = blockIdx.x;
    const int bh = id & 31, cb = id >> 5, c0 = cb * 16;
    const int l = threadIdx.x;
    const int quad = (l >> 4) & 3, ln15 = l & 15, q8 = quad * 8;
    const int hi = l >> 5;

    __shared__ unsigned short knR[4392];   // row i at i*136 + (i>>3)*16 (bank-staggered)
    __shared__ unsigned short Xt[16][40];
    __shared__ unsigned short ut[16][40];

    const f32x4 Z = {0.f, 0.f, 0.f, 0.f};
    f32x4 Sacc[8];
#pragma unroll
    for (int t = 0; t < 8; ++t) Sacc[t] = Z;

    const size_t bhL = (size_t)bh * L_SEQ;
    const int a0 = (((l & 16) << 1) | ln15) << 2;   // bperm byte addr, quads 0/1
    const int a1 = a0 + 64;                          // quads 2/3

    bf16x8 kAa[2][4], kAb[2][4];
    bf16x8 qA[2][4], tA[2], aA[2], knA[8], uB;
    float vr[8], br[8];

    auto loadK = [&](int ch, bf16x8 (&kA)[2][4]){
        const unsigned short* kp = kw + (bhL + (size_t)ch * CHUNK) * DK;
#pragma unroll
        for (int mt = 0; mt < 2; ++mt)
#pragma unroll
        for (int ks = 0; ks < 4; ++ks)
            kA[mt][ks] = *(const bf16x8*)(kp + (16*mt + ln15) * DK + 32*ks + q8);
    };
    auto loadQ = [&](int ch){
        const unsigned short* qp = qw + (bhL + (size_t)ch * CHUNK) * DK;
#pragma unroll
        for (int mt = 0; mt < 2; ++mt)
#pragma unroll
        for (int ks = 0; ks < 4; ++ks)
            qA[mt][ks] = *(const bf16x8*)(qp + (16*mt + ln15) * DK + 32*ks + q8);
    };
    auto loadT = [&](int ch){
        const unsigned short* Tp = Tw + ((size_t)(bh * NCH + ch) << 10);
#pragma unroll
        for (int mt = 0; mt < 2; ++mt)
            tA[mt] = *(const bf16x8*)(Tp + (16*mt + ln15) * 32 + q8);
    };
    auto loadA = [&](int ch){
        const unsigned short* Ap = Aw + ((size_t)(bh * NCH + ch) << 10);
#pragma unroll
        for (int mt = 0; mt < 2; ++mt)
            aA[mt] = *(const bf16x8*)(Ap + (16*mt + ln15) * 32 + q8);
    };
    auto loadVB = [&](int ch){
        const size_t row0 = bhL + (size_t)ch * CHUNK;
#pragma unroll
        for (int g = 0; g < 8; ++g){
            int i = 16*(g >> 2) + 4*quad + (g & 3);
            vr[g] = v[(row0 + i) * DV + c0 + ln15];
            br[g] = beta[row0 + i];
        }
    };

    // prologue: chunk 0 operands + kn(1); zero pipeline state
    loadK(0, kAa);
    loadQ(0); loadT(0); loadA(0); loadVB(0);
    loadK(1, kAb);
    {
        U8 z; z.u[0] = 0u; z.u[1] = 0u; z.u[2] = 0u; z.u[3] = 0u;
        uB = z.v;
#pragma unroll
        for (int t = 0; t < 8; ++t) knA[t] = z.v;
    }

    auto body = [&](int ch, bf16x8 (&cur)[2][4]){
        const size_t row0 = bhL + (size_t)ch * CHUNK;

        // (1) S update with previous chunk's knT and U (zero contribution at ch=0)
#pragma unroll
        for (int t = 0; t < 8; ++t)
            Sacc[t] = MFMA16(knA[t], uB, Sacc[t]);

        // (2) S -> packed bf16 pairs
        int P[8][2];
#pragma unroll
        for (int t = 0; t < 8; ++t){
            P[t][0] = (int)pk2(Sacc[t][0], Sacc[t][1]);
            P[t][1] = (int)pk2(Sacc[t][2], Sacc[t][3]);
        }
        // (3) S B-frags via quad-bpermute
        bf16x8 SB[4];
#pragma unroll
        for (int ks = 0; ks < 4; ++ks){
            U8 sb;
            int e, f;
            e = __builtin_amdgcn_ds_bpermute(a0, P[2*ks][0]);
            f = __builtin_amdgcn_ds_bpermute(a0, P[2*ks+1][0]);
            sb.u[0] = (unsigned)(hi ? f : e);
            e = __builtin_amdgcn_ds_bpermute(a0, P[2*ks][1]);
            f = __builtin_amdgcn_ds_bpermute(a0, P[2*ks+1][1]);
            sb.u[1] = (unsigned)(hi ? f : e);
            e = __builtin_amdgcn_ds_bpermute(a1, P[2*ks][0]);
            f = __builtin_amdgcn_ds_bpermute(a1, P[2*ks+1][0]);
            sb.u[2] = (unsigned)(hi ? f : e);
            e = __builtin_amdgcn_ds_bpermute(a1, P[2*ks][1]);
            f = __builtin_amdgcn_ds_bpermute(a1, P[2*ks+1][1]);
            sb.u[3] = (unsigned)(hi ? f : e);
            SB[ks] = sb.v;
        }

        // (4) Y = kn @ S ; Opart = qn @ S (interleaved, independent chains)
        f32x4 Y[2] = {Z, Z}, Op[2] = {Z, Z};
#pragma unroll
        for (int ks = 0; ks < 4; ++ks)
#pragma unroll
        for (int mt = 0; mt < 2; ++mt){
            Y[mt]  = MFMA16(cur[mt][ks], SB[ks], Y[mt]);
            Op[mt] = MFMA16(qA[mt][ks],  SB[ks], Op[mt]);
        }

        // (5) X = beta*(v - Y)  -> Xt (c x i)
#pragma unroll
        for (int mt = 0; mt < 2; ++mt){
            unsigned int w0 = pk2(br[4*mt+0] * (vr[4*mt+0] - Y[mt][0]),
                                  br[4*mt+1] * (vr[4*mt+1] - Y[mt][1]));
            unsigned int w1 = pk2(br[4*mt+2] * (vr[4*mt+2] - Y[mt][2]),
                                  br[4*mt+3] * (vr[4*mt+3] - Y[mt][3]));
            *(unsigned int*)&Xt[ln15][16*mt + 4*quad]     = w0;
            *(unsigned int*)&Xt[ln15][16*mt + 4*quad + 2] = w1;
        }

        // (6) stage kn rows -> knR (consumed by the transposed gathers below)
#pragma unroll
        for (int mt = 0; mt < 2; ++mt)
#pragma unroll
        for (int ks = 0; ks < 4; ++ks){
            int i = 16*mt + ln15;
            int ad = i * 136 + (i >> 3) * 16 + 32*ks + q8;
            *(bf16x8*)&knR[ad] = cur[mt][ks];
        }

        // (7) X B-frag (DS in-order: no drain needed, compiler counts the wait)
        bf16x8 Xb = *(const bf16x8*)&Xt[ln15][q8];

        // (8) knT gather, low half — fills the Xt round-trip shadow
        unsigned int rja[32];
#pragma unroll
        for (int t = 0; t < 4; ++t)
#pragma unroll
        for (int j = 0; j < 8; ++j)
            rja[8*t + j] = knR[(q8 + j) * 136 + ((q8 + j) >> 3) * 16 + 16*t + ln15];

        // (9) U = T @ X
        f32x4 U[2];
#pragma unroll
        for (int mt = 0; mt < 2; ++mt) U[mt] = MFMA16(tA[mt], Xb, Z);

        // (10) U -> ut
#pragma unroll
        for (int mt = 0; mt < 2; ++mt){
            *(unsigned int*)&ut[ln15][16*mt + 4*quad]     = pk2(U[mt][0], U[mt][1]);
            *(unsigned int*)&ut[ln15][16*mt + 4*quad + 2] = pk2(U[mt][2], U[mt][3]);
        }

        // (10.5) pack low knA (reads long since landed; frees the regs)
#pragma unroll
        for (int t = 0; t < 4; ++t){
            U8 kk;
            kk.u[0] = rja[8*t+0] | (rja[8*t+1] << 16);
            kk.u[1] = rja[8*t+2] | (rja[8*t+3] << 16);
            kk.u[2] = rja[8*t+4] | (rja[8*t+5] << 16);
            kk.u[3] = rja[8*t+6] | (rja[8*t+7] << 16);
            knA[t] = kk.v;
        }

        // (11) U B-frag
        uB = *(const bf16x8*)&ut[ln15][q8];

        // (11.5) prefetch next chunk's operands (VMEM only — doesn't touch lgkm);
        //        attn is deferred past its last use at (13). kn(ch+2) reuses cur.
        const int chn = (ch + 1 < NCH) ? ch + 1 : NCH - 1;
        const int ch2 = (ch + 2 < NCH) ? ch + 2 : NCH - 1;
        loadQ(chn); loadT(chn); loadVB(chn);
        loadK(ch2, cur);

        // (12) knT gather, high half — fills the ut round-trip shadow
        unsigned int rjb[32];
#pragma unroll
        for (int t = 0; t < 4; ++t)
#pragma unroll
        for (int j = 0; j < 8; ++j)
            rjb[8*t + j] = knR[(q8 + j) * 136 + ((q8 + j) >> 3) * 16 + 16*(t + 4) + ln15];

        // (13) O = Opart + attn @ U ; (14) store
        f32x4 O[2];
#pragma unroll
        for (int mt = 0; mt < 2; ++mt) O[mt] = MFMA16(aA[mt], uB, Op[mt]);
#pragma unroll
        for (int mt = 0; mt < 2; ++mt)
#pragma unroll
        for (int rg = 0; rg < 4; ++rg)
            out[(row0 + 16*mt + 4*quad + rg) * DV + c0 + ln15] = O[mt][rg];

        // (15) pack high knA ; attn prefetch (past its use)
#pragma unroll
        for (int t = 0; t < 4; ++t){
            U8 kk;
            kk.u[0] = rjb[8*t+0] | (rjb[8*t+1] << 16);
            kk.u[1] = rjb[8*t+2] | (rjb[8*t+3] << 16);
            kk.u[2] = rjb[8*t+4] | (rjb[8*t+5] << 16);
            kk.u[3] = rjb[8*t+6] | (rjb[8*t+7] << 16);
            knA[t + 4] = kk.v;
        }
        loadA(chn);
    };

    for (int ch = 0; ch < NCH; ch += 2){
        body(ch,     kAa);
        body(ch + 1, kAb);
    }
}

// ---------------- Fallback (round-1 fused kernel) if ws too small ----------

__global__ __launch_bounds__(512, 1)
void deltanet_fused(const float* __restrict__ q, const float* __restrict__ k,
                    const float* __restrict__ v, const float* __restrict__ beta,
                    float* __restrict__ out)
{
    const int bh = blockIdx.x;
    const int tid = threadIdx.x;
    const int n = L_SEQ / CHUNK;

    __shared__ float S[DK][DV + 1];
    __shared__ float qs[CHUNK][DK + 1];
    __shared__ float ks[CHUNK][DK + 1];
    __shared__ float vs[CHUNK][DV + 1];
    __shared__ float kbs[CHUNK][DK + 1];
    __shared__ float T[CHUNK][CHUNK + 1];
    __shared__ float at[CHUNK][CHUNK + 1];
    __shared__ float bet[CHUNK];

    for (int idx = tid; idx < DK * DV; idx += 512)
        S[idx / DV][idx % DV] = 0.f;
    __syncthreads();

    const size_t base_bh = (size_t)bh * L_SEQ;

    for (int ch = 0; ch < n; ++ch){
        const size_t row0 = base_bh + (size_t)ch * CHUNK;
        for (int idx = tid; idx < CHUNK * DK; idx += 512){
            int r = idx >> 7, c = idx & 127;
            size_t g = (row0 + (size_t)r) * DK + c;
            qs[r][c] = q[g]; ks[r][c] = k[g]; vs[r][c] = v[g];
        }
        if (tid < CHUNK) bet[tid] = beta[row0 + tid];
        __syncthreads();
        if (tid < 64){
            int r = tid & 31;
            const float* src = (tid < 32) ? &qs[r][0] : &ks[r][0];
            float s = 0.f;
            for (int d = 0; d < DK; ++d){ float x = src[d]; s += x * x; }
            at[(tid < 32) ? 0 : 1][r] = 1.0f / sqrtf(s + 1e-6f);
        }
        __syncthreads();
        for (int idx = tid; idx < CHUNK * DK; idx += 512){
            int r = idx >> 7, c = idx & 127;
            float qq = qs[r][c] * at[0][r];
            float kk = ks[r][c] * at[1][r];
            float b = bet[r];
            qs[r][c] = qq; ks[r][c] = kk; kbs[r][c] = kk * b; vs[r][c] *= b;
        }
        __syncthreads();
        for (int idx = tid; idx < CHUNK * CHUNK; idx += 512){
            int i = idx >> 5, j = idx & 31;
            float s = 0.f;
            if (j < i){
                for (int d = 0; d < DK; ++d) s += kbs[i][d] * ks[j][d];
                s = -s;
            }
            T[i][j] = s;
        }
        __syncthreads();
        for (int i = 1; i < CHUNK; ++i){
            float upd = 0.f;
            if (tid < i){
                int j = tid;
                for (int kk = j + 1; kk < i; ++kk) upd += T[i][kk] * T[kk][j];
            }
            __syncthreads();
            if (tid < i) T[i][tid] += upd;
            __syncthreads();
        }
        if (tid < CHUNK) T[tid][tid] = 1.0f;
        __syncthreads();
        {
            int c = tid & 127;
            int i0 = (tid >> 7) * 8;
            float uacc[8], wacc[8];
#pragma unroll
            for (int r = 0; r < 8; ++r){ uacc[r] = 0.f; wacc[r] = 0.f; }
            for (int j = 0; j < CHUNK; ++j){
                float vvv = vs[j][c], kb = kbs[j][c];
#pragma unroll
                for (int r = 0; r < 8; ++r){
                    float tt = T[i0 + r][j];
                    uacc[r] += tt * vvv; wacc[r] += tt * kb;
                }
            }
            __syncthreads();
#pragma unroll
            for (int r = 0; r < 8; ++r){ vs[i0 + r][c] = uacc[r]; kbs[i0 + r][c] = wacc[r]; }
        }
        __syncthreads();
        for (int idx = tid; idx < CHUNK * CHUNK; idx += 512){
            int i = idx >> 5, j = idx & 31;
            float s = 0.f;
            if (j <= i) for (int d = 0; d < DK; ++d) s += qs[i][d] * ks[j][d];
            at[i][j] = s;
        }
        __syncthreads();
        {
            int c = tid & 127;
            int i0 = (tid >> 7) * 8;
            float acc[8];
#pragma unroll
            for (int r = 0; r < 8; ++r) acc[r] = 0.f;
            for (int d = 0; d < DK; ++d){
                float sv = S[d][c];
#pragma unroll
                for (int r = 0; r < 8; ++r) acc[r] += kbs[i0 + r][d] * sv;
            }
#pragma unroll
            for (int r = 0; r < 8; ++r) vs[i0 + r][c] -= acc[r];
        }
        __syncthreads();
        {
            int c = tid & 127;
            int i0 = (tid >> 7) * 8;
            float acc[8];
#pragma unroll
            for (int r = 0; r < 8; ++r) acc[r] = 0.f;
            for (int d = 0; d < DK; ++d){
                float sv = S[d][c];
#pragma unroll
                for (int r = 0; r < 8; ++r) acc[r] += qs[i0 + r][d] * sv;
            }
            for (int j = 0; j < CHUNK; ++j){
                float uv = vs[j][c];
#pragma unroll
                for (int r = 0; r < 8; ++r) acc[r] += at[i0 + r][j] * uv;
            }
#pragma unroll
            for (int r = 0; r < 8; ++r)
                out[(row0 + (size_t)(i0 + r)) * DV + c] = acc[r];
        }
        __syncthreads();
        {
            int c = tid & 127;
            int d0 = (tid >> 7) * 32;
            float acc[32];
#pragma unroll
            for (int r = 0; r < 32; ++r) acc[r] = 0.f;
            for (int i = 0; i < CHUNK; ++i){
                float uv = vs[i][c];
#pragma unroll
                for (int r = 0; r < 32; ++r) acc[r] += ks[i][d0 + r] * uv;
            }
#pragma unroll
            for (int r = 0; r < 32; ++r) S[d0 + r][c] += acc[r];
        }
        __syncthreads();
    }
}

extern "C" void kernel_launch(void* const* d_in, const int* in_sizes, int n_in,
                              void* d_out, int out_size, void* d_ws, size_t ws_size,
                              hipStream_t stream) {
    const float* q = (const float*)d_in[0];
    const float* k = (const float*)d_in[1];
    const float* v = (const float*)d_in[2];
    const float* beta = (const float*)d_in[3];
    float* out = (float*)d_out;

    const size_t QK = (size_t)BH * L_SEQ * DK;       // 16,777,216
    const size_t TA = (size_t)BH * NCH * 1024;       //  4,194,304
    const size_t need = (2 * QK + 2 * TA) * sizeof(unsigned short); // ~84 MB

    if (ws_size >= need){
        unsigned short* qwp = (unsigned short*)d_ws;
        unsigned short* kwp = qwp + QK;
        unsigned short* Twp = kwp + QK;
        unsigned short* Awp = Twp + TA;
        prep_kernel<<<BH * NCH, 64, 0, stream>>>(q, k, beta, qwp, kwp, Twp, Awp);
        scan_kernel<<<BH * 8, 64, 0, stream>>>(v, beta, qwp, kwp, Twp, Awp, out);
    } else {
        deltanet_fused<<<BH, 512, 0, stream>>>(q, k, v, beta, out);
    }
}

// Round 2
// 364.909 us; speedup vs baseline: 1.3445x; 1.0111x over previous
//
#include <hip/hip_runtime.h>
#include <math.h>

#define CHUNK 32
#define DK 128
#define DV 128
#define L_SEQ 4096
#define BH 32
#define NCH 128

typedef __attribute__((ext_vector_type(8))) short bf16x8;
typedef __attribute__((ext_vector_type(4))) float f32x4;

union U8 { unsigned int u[4]; bf16x8 v; };

#define MFMA16(a, b, c) __builtin_amdgcn_mfma_f32_16x16x32_bf16((a), (b), (c), 0, 0, 0)
#define LGKM_WAIT() __asm__ __volatile__("s_waitcnt lgkmcnt(0)" ::: "memory")

__device__ __forceinline__ unsigned short f2bf(float x){
    unsigned int u = __builtin_bit_cast(unsigned int, x);
    u = u + 0x7FFFu + ((u >> 16) & 1u);   // RNE
    return (unsigned short)(u >> 16);
}
// RNE pack of two f32 -> packed bf16 pair, single HW instruction.
__device__ __forceinline__ unsigned int pk2(float a, float b){
    unsigned int r;
    asm("v_cvt_pk_bf16_f32 %0, %1, %2" : "=v"(r) : "v"(a), "v"(b));
    return r;
}

__device__ __forceinline__ bf16x8 afragF32(const float (*M)[36], int row, int q8){
    float4 f0 = *(const float4*)&M[row][q8];
    float4 f1 = *(const float4*)&M[row][q8 + 4];
    U8 t;
    t.u[0] = pk2(f0.x, f0.y); t.u[1] = pk2(f0.z, f0.w);
    t.u[2] = pk2(f1.x, f1.y); t.u[3] = pk2(f1.z, f1.w);
    return t.v;
}
__device__ __forceinline__ bf16x8 bfragF32(const float (*M)[36], int q8, int col){
    U8 t;
#pragma unroll
    for (int j2 = 0; j2 < 4; ++j2)
        t.u[j2] = pk2(M[q8 + 2*j2][col], M[q8 + 2*j2 + 1][col]);
    return t.v;
}

// ---------------- Phase 1: per-chunk prep, register-direct fragments -------
// One 64-thread block per (bh,chunk). Lanes load q/k rows directly in MFMA
// A/B-frag layout (row 16mt+ln15, cols 32ks+q8..+7): no input LDS staging.
// Row L2-norm via shfl_xor(16)+shfl_xor(32). LDS = Ms/Rs (9.2KB) + optional
// 8.8KB transpose stage for kwT => ~8 blocks/CU (was 4).
// Outputs: qw/kw (bf16 rows), Tw=(I+A)^-1, Aw=tril(qn kn^T), kwT=kn^T [d][i].

template<bool WKT>
__global__ __launch_bounds__(64)
void prep_kernel(const float* __restrict__ q, const float* __restrict__ k,
                 const float* __restrict__ beta,
                 unsigned short* __restrict__ qw, unsigned short* __restrict__ kw,
                 unsigned short* __restrict__ Tw, unsigned short* __restrict__ Aw,
                 unsigned short* __restrict__ kwT)
{
    const int bc = blockIdx.x;               // bh*NCH + ch
    const size_t row0 = (size_t)bc * CHUNK;
    const int l = threadIdx.x;
    const int quad = (l >> 4) & 3, ln15 = l & 15, q8 = quad * 8;

    __shared__ float Ms[32][36];
    __shared__ float Rs[32][36];
    __shared__ unsigned short knS[WKT ? 4392 : 2];

    const float bet0 = beta[row0 + ln15];
    const float bet1 = beta[row0 + 16 + ln15];

    // ---- q: load frag-layout, rownorm, pack, store ----
    bf16x8 qF[2][4];
    {
        float4 raw[2][4][2];
        float s0 = 0.f, s1 = 0.f;
#pragma unroll
        for (int mt = 0; mt < 2; ++mt)
#pragma unroll
        for (int ks = 0; ks < 4; ++ks){
            const float* p = q + (row0 + 16*mt + ln15) * DK + 32*ks + q8;
            raw[mt][ks][0] = *(const float4*)p;
            raw[mt][ks][1] = *(const float4*)(p + 4);
        }
#pragma unroll
        for (int ks = 0; ks < 4; ++ks)
#pragma unroll
        for (int h = 0; h < 2; ++h){
            float4 a = raw[0][ks][h], b = raw[1][ks][h];
            s0 += a.x*a.x + a.y*a.y + a.z*a.z + a.w*a.w;
            s1 += b.x*b.x + b.y*b.y + b.z*b.z + b.w*b.w;
        }
        s0 += __shfl_xor(s0, 16); s0 += __shfl_xor(s0, 32);
        s1 += __shfl_xor(s1, 16); s1 += __shfl_xor(s1, 32);
        float sc0 = rsqrtf(s0 + 1e-6f), sc1 = rsqrtf(s1 + 1e-6f);
#pragma unroll
        for (int mt = 0; mt < 2; ++mt){
            float sc = mt ? sc1 : sc0;
#pragma unroll
            for (int ks = 0; ks < 4; ++ks){
                float4 a = raw[mt][ks][0], b = raw[mt][ks][1];
                U8 t;
                t.u[0] = pk2(a.x*sc, a.y*sc); t.u[1] = pk2(a.z*sc, a.w*sc);
                t.u[2] = pk2(b.x*sc, b.y*sc); t.u[3] = pk2(b.z*sc, b.w*sc);
                qF[mt][ks] = t.v;
                *(bf16x8*)(qw + (row0 + 16*mt + ln15) * DK + 32*ks + q8) = t.v;
            }
        }
    }
    // ---- k: kn + kb = kn*beta ----
    bf16x8 kF[2][4], kB[2][4];
    {
        float4 raw[2][4][2];
        float s0 = 0.f, s1 = 0.f;
#pragma unroll
        for (int mt = 0; mt < 2; ++mt)
#pragma unroll
        for (int ks = 0; ks < 4; ++ks){
            const float* p = k + (row0 + 16*mt + ln15) * DK + 32*ks + q8;
            raw[mt][ks][0] = *(const float4*)p;
            raw[mt][ks][1] = *(const float4*)(p + 4);
        }
#pragma unroll
        for (int ks = 0; ks < 4; ++ks)
#pragma unroll
        for (int h = 0; h < 2; ++h){
            float4 a = raw[0][ks][h], b = raw[1][ks][h];
            s0 += a.x*a.x + a.y*a.y + a.z*a.z + a.w*a.w;
            s1 += b.x*b.x + b.y*b.y + b.z*b.z + b.w*b.w;
        }
        s0 += __shfl_xor(s0, 16); s0 += __shfl_xor(s0, 32);
        s1 += __shfl_xor(s1, 16); s1 += __shfl_xor(s1, 32);
        float sc0 = rsqrtf(s0 + 1e-6f), sc1 = rsqrtf(s1 + 1e-6f);
#pragma unroll
        for (int mt = 0; mt < 2; ++mt){
            float sc = mt ? sc1 : sc0;
            float bb = mt ? bet1 : bet0;
#pragma unroll
            for (int ks = 0; ks < 4; ++ks){
                float4 a = raw[mt][ks][0], b = raw[mt][ks][1];
                float x0=a.x*sc, x1=a.y*sc, x2=a.z*sc, x3=a.w*sc;
                float x4=b.x*sc, x5=b.y*sc, x6=b.z*sc, x7=b.w*sc;
                U8 t, tb;
                t.u[0]=pk2(x0,x1); t.u[1]=pk2(x2,x3); t.u[2]=pk2(x4,x5); t.u[3]=pk2(x6,x7);
                tb.u[0]=pk2(x0*bb,x1*bb); tb.u[1]=pk2(x2*bb,x3*bb);
                tb.u[2]=pk2(x4*bb,x5*bb); tb.u[3]=pk2(x6*bb,x7*bb);
                kF[mt][ks] = t.v; kB[mt][ks] = tb.v;
                *(bf16x8*)(kw + (row0 + 16*mt + ln15) * DK + 32*ks + q8) = t.v;
            }
        }
    }

    // stage kn rows for the kwT transpose (gathered after the MFMA phase)
    if constexpr (WKT){
#pragma unroll
        for (int mt = 0; mt < 2; ++mt)
#pragma unroll
        for (int ks = 0; ks < 4; ++ks){
            int i = 16*mt + ln15;
            int ad = i * 136 + (i >> 3) * 16 + 32*ks + q8;
            *(bf16x8*)&knS[ad] = kF[mt][ks];
        }
    }

    // ---- B = kb @ kn^T ; attn = qn @ kn^T  (MFMA, K=128, all in-register) --
    f32x4 Z = {0.f, 0.f, 0.f, 0.f};
    f32x4 Bacc[2][2] = {{Z, Z}, {Z, Z}};
    f32x4 Aacc[2][2] = {{Z, Z}, {Z, Z}};
#pragma unroll
    for (int ks = 0; ks < 4; ++ks)
#pragma unroll
    for (int mt = 0; mt < 2; ++mt)
#pragma unroll
    for (int nt = 0; nt < 2; ++nt){
        Bacc[mt][nt] = MFMA16(kB[mt][ks], kF[nt][ks], Bacc[mt][nt]);
        Aacc[mt][nt] = MFMA16(qF[mt][ks], kF[nt][ks], Aacc[mt][nt]);
    }

    // ---- masks; store attn; stage B; init R = I + B ----
    f32x4 Rc[2][2];
#pragma unroll
    for (int mt = 0; mt < 2; ++mt)
#pragma unroll
    for (int nt = 0; nt < 2; ++nt)
#pragma unroll
    for (int rg = 0; rg < 4; ++rg){
        int row = 16*mt + 4*quad + rg, col = 16*nt + ln15;
        float av = (col <= row) ? Aacc[mt][nt][rg] : 0.f;
        Aw[((size_t)bc << 10) + row*32 + col] = f2bf(av);
        float bm = (col < row) ? -Bacc[mt][nt][rg] : 0.f;
        Ms[row][col] = bm;
        Rc[mt][nt][rg] = bm + ((col == row) ? 1.f : 0.f);
    }

    // ---- kwT: gather transposed kn frags from knS, store coalesced ----
    if constexpr (WKT){
        unsigned short* kT = kwT + ((size_t)bc << 12);
#pragma unroll
        for (int t = 0; t < 8; ++t){
            unsigned short rj[8];
#pragma unroll
            for (int j = 0; j < 8; ++j)
                rj[j] = knS[(q8 + j) * 136 + ((q8 + j) >> 3) * 16 + 16*t + ln15];
            U8 kk;
            kk.u[0] = (unsigned)rj[0] | ((unsigned)rj[1] << 16);
            kk.u[1] = (unsigned)rj[2] | ((unsigned)rj[3] << 16);
            kk.u[2] = (unsigned)rj[4] | ((unsigned)rj[5] << 16);
            kk.u[3] = (unsigned)rj[6] | ((unsigned)rj[7] << 16);
            *(bf16x8*)(kT + (16*t + ln15) * 32 + q8) = kk.v;
        }
    }

    // ---- doubling: R <- R(I+B^2)(I+B^4)(I+B^8)(I+B^16) ----
#pragma unroll 1
    for (int rd = 0; rd < 4; ++rd){
        LGKM_WAIT();
        bf16x8 Am[2], Bm2[2];
#pragma unroll
        for (int mt = 0; mt < 2; ++mt) Am[mt] = afragF32(Ms, 16*mt + ln15, q8);
#pragma unroll
        for (int nt = 0; nt < 2; ++nt) Bm2[nt] = bfragF32(Ms, q8, 16*nt + ln15);
        f32x4 Mq[2][2];
#pragma unroll
        for (int mt = 0; mt < 2; ++mt)
#pragma unroll
        for (int nt = 0; nt < 2; ++nt)
            Mq[mt][nt] = MFMA16(Am[mt], Bm2[nt], Z);
#pragma unroll
        for (int mt = 0; mt < 2; ++mt)
#pragma unroll
        for (int nt = 0; nt < 2; ++nt)
#pragma unroll
        for (int rg = 0; rg < 4; ++rg){
            int row = 16*mt + 4*quad + rg, col = 16*nt + ln15;
            Rs[row][col] = Rc[mt][nt][rg];
            Ms[row][col] = Mq[mt][nt][rg];
        }
        LGKM_WAIT();
        bf16x8 Ar[2], Bq[2];
#pragma unroll
        for (int mt = 0; mt < 2; ++mt) Ar[mt] = afragF32(Rs, 16*mt + ln15, q8);
#pragma unroll
        for (int nt = 0; nt < 2; ++nt) Bq[nt] = bfragF32(Ms, q8, 16*nt + ln15);
#pragma unroll
        for (int mt = 0; mt < 2; ++mt)
#pragma unroll
        for (int nt = 0; nt < 2; ++nt)
            Rc[mt][nt] = MFMA16(Ar[mt], Bq[nt], Rc[mt][nt]);   // R += R~ * M^2
    }

    // ---- store T ----
#pragma unroll
    for (int mt = 0; mt < 2; ++mt)
#pragma unroll
    for (int nt = 0; nt < 2; ++nt)
#pragma unroll
    for (int rg = 0; rg < 4; ++rg){
        int row = 16*mt + 4*quad + rg, col = 16*nt + ln15;
        Tw[((size_t)bc << 10) + row*32 + col] = f2bf(Rc[mt][nt][rg]);
    }
}

// ---------------- Phase 2 (fast): zero-LDS sequential scan -----------------
// 1 wave/block, no barriers, no allocated LDS. knT frags come from kwT
// (coalesced 16B loads, prefetched a body ahead); every C-frag -> B-frag
// redistribution (S, X, U) done with the quad-bpermute pattern.

__global__ __launch_bounds__(64, 1)
void scan_fast(const float* __restrict__ v, const float* __restrict__ beta,
               const unsigned short* __restrict__ qw, const unsigned short* __restrict__ kw,
               const unsigned short* __restrict__ kwT,
               const unsigned short* __restrict__ Tw, const unsigned short* __restrict__ Aw,
               float* __restrict__ out)
{
    const int id = blockIdx.x;
    const int bh = id & 31, cb = id >> 5, c0 = cb * 16;
    const int l = threadIdx.x;
    const int quad = (l >> 4) & 3, ln15 = l & 15, q8 = quad * 8;
    const int hi = l >> 5;

    const f32x4 Z = {0.f, 0.f, 0.f, 0.f};
    f32x4 Sacc[8];
#pragma unroll
    for (int t = 0; t < 8; ++t) Sacc[t] = Z;

    const size_t bhL = (size_t)bh * L_SEQ;
    const int a0 = (((l & 16) << 1) | ln15) << 2;   // src lane 32*(q&1)+ln15
    const int a1 = a0 + 64;                          // +16 lanes

    bf16x8 cur[2][4], qA[2][4], knA[8], tA[2], aA[2], uB;
    float vr[8], br[8];

    // C-frag (rows 16m+4q+rg @ col ln15) -> B-frag (k=q8+j @ col ln15).
    // p0/p1 = mt0 pairs (rg01, rg23); p2/p3 = mt1 pairs. Verified vs the
    // original ut/Xt LDS round-trip lane-by-lane (bitwise identical).
    auto quadswap = [&](int p0, int p1, int p2, int p3) -> bf16x8 {
        U8 r; int e, f;
        e = __builtin_amdgcn_ds_bpermute(a0, p0); f = __builtin_amdgcn_ds_bpermute(a0, p2);
        r.u[0] = (unsigned)(hi ? f : e);
        e = __builtin_amdgcn_ds_bpermute(a0, p1); f = __builtin_amdgcn_ds_bpermute(a0, p3);
        r.u[1] = (unsigned)(hi ? f : e);
        e = __builtin_amdgcn_ds_bpermute(a1, p0); f = __builtin_amdgcn_ds_bpermute(a1, p2);
        r.u[2] = (unsigned)(hi ? f : e);
        e = __builtin_amdgcn_ds_bpermute(a1, p1); f = __builtin_amdgcn_ds_bpermute(a1, p3);
        r.u[3] = (unsigned)(hi ? f : e);
        return r.v;
    };

    auto loadK = [&](int ch){
        const unsigned short* kp = kw + (bhL + (size_t)ch * CHUNK) * DK;
#pragma unroll
        for (int mt = 0; mt < 2; ++mt)
#pragma unroll
        for (int ks = 0; ks < 4; ++ks)
            cur[mt][ks] = *(const bf16x8*)(kp + (16*mt + ln15) * DK + 32*ks + q8);
    };
    auto loadQ = [&](int ch){
        const unsigned short* qp = qw + (bhL + (size_t)ch * CHUNK) * DK;
#pragma unroll
        for (int mt = 0; mt < 2; ++mt)
#pragma unroll
        for (int ks = 0; ks < 4; ++ks)
            qA[mt][ks] = *(const bf16x8*)(qp + (16*mt + ln15) * DK + 32*ks + q8);
    };
    auto loadT = [&](int ch){
        const unsigned short* Tp = Tw + ((size_t)(bh * NCH + ch) << 10);
#pragma unroll
        for (int mt = 0; mt < 2; ++mt)
            tA[mt] = *(const bf16x8*)(Tp + (16*mt + ln15) * 32 + q8);
    };
    auto loadA = [&](int ch){
        const unsigned short* Ap = Aw + ((size_t)(bh * NCH + ch) << 10);
#pragma unroll
        for (int mt = 0; mt < 2; ++mt)
            aA[mt] = *(const bf16x8*)(Ap + (16*mt + ln15) * 32 + q8);
    };
    auto loadVB = [&](int ch){
        const size_t row0 = bhL + (size_t)ch * CHUNK;
#pragma unroll
        for (int g = 0; g < 8; ++g){
            int i = 16*(g >> 2) + 4*quad + (g & 3);
            vr[g] = v[(row0 + i) * DV + c0 + ln15];
            br[g] = beta[row0 + i];
        }
    };
    auto loadKT = [&](int ch){
        const unsigned short* p = kwT + ((size_t)(bh * NCH + ch) << 12);
#pragma unroll
        for (int t = 0; t < 8; ++t)
            knA[t] = *(const bf16x8*)(p + (16*t + ln15) * 32 + q8);
    };

    // prologue: chunk-0 operands; zero pipeline state (knA MUST be zeroed:
    // NaN*0 = NaN in MFMA)
    loadK(0); loadQ(0); loadT(0); loadA(0); loadVB(0);
    {
        U8 z; z.u[0] = 0u; z.u[1] = 0u; z.u[2] = 0u; z.u[3] = 0u;
        uB = z.v;
#pragma unroll
        for (int t = 0; t < 8; ++t) knA[t] = z.v;
    }

    for (int ch = 0; ch < NCH; ++ch){
        const size_t row0 = bhL + (size_t)ch * CHUNK;
        const int chn = (ch + 1 < NCH) ? ch + 1 : NCH - 1;

        // (1) S += kn(ch-1)^T @ U(ch-1)   (zero contribution at ch=0)
#pragma unroll
        for (int t = 0; t < 8; ++t)
            Sacc[t] = MFMA16(knA[t], uB, Sacc[t]);

        // (1b) prefetch knT(ch) for next body's (1)
        loadKT(ch);

        // (2) S -> packed bf16 pairs ; (3) B-frags via quad-bpermute
        int P[8][2];
#pragma unroll
        for (int t = 0; t < 8; ++t){
            P[t][0] = (int)pk2(Sacc[t][0], Sacc[t][1]);
            P[t][1] = (int)pk2(Sacc[t][2], Sacc[t][3]);
        }
        bf16x8 SB[4];
#pragma unroll
        for (int ks = 0; ks < 4; ++ks)
            SB[ks] = quadswap(P[2*ks][0], P[2*ks][1], P[2*ks+1][0], P[2*ks+1][1]);

        // (4) Y = kn @ S ; Opart = qn @ S (independent chains, interleaved)
        f32x4 Y[2] = {Z, Z}, Op[2] = {Z, Z};
#pragma unroll
        for (int ks = 0; ks < 4; ++ks)
#pragma unroll
        for (int mt = 0; mt < 2; ++mt){
            Y[mt]  = MFMA16(cur[mt][ks], SB[ks], Y[mt]);
            Op[mt] = MFMA16(qA[mt][ks],  SB[ks], Op[mt]);
        }

        // (4b) prefetch kn/q(ch+1) (cur/qA free after (4))
        loadK(chn); loadQ(chn);

        // (5) X = beta*(v - Y) -> packed pairs -> B-frag via bpermute
        int PX0, PX1, PX2, PX3;
        {
            float x00 = br[0]*(vr[0]-Y[0][0]), x01 = br[1]*(vr[1]-Y[0][1]);
            float x02 = br[2]*(vr[2]-Y[0][2]), x03 = br[3]*(vr[3]-Y[0][3]);
            float x10 = br[4]*(vr[4]-Y[1][0]), x11 = br[5]*(vr[5]-Y[1][1]);
            float x12 = br[6]*(vr[6]-Y[1][2]), x13 = br[7]*(vr[7]-Y[1][3]);
            PX0 = (int)pk2(x00, x01); PX1 = (int)pk2(x02, x03);
            PX2 = (int)pk2(x10, x11); PX3 = (int)pk2(x12, x13);
        }
        bf16x8 Xb = quadswap(PX0, PX1, PX2, PX3);

        // (9) U = T @ X
        f32x4 U[2];
#pragma unroll
        for (int mt = 0; mt < 2; ++mt) U[mt] = MFMA16(tA[mt], Xb, Z);

        // (9b) prefetch T(ch+1)
        loadT(chn);

        // (10) U -> B-frag via bpermute (carried into next body's (1))
        {
            int PU0 = (int)pk2(U[0][0], U[0][1]), PU1 = (int)pk2(U[0][2], U[0][3]);
            int PU2 = (int)pk2(U[1][0], U[1][1]), PU3 = (int)pk2(U[1][2], U[1][3]);
            uB = quadswap(PU0, PU1, PU2, PU3);
        }

        // (13) O = Opart + attn @ U ; store
        f32x4 O[2];
#pragma unroll
        for (int mt = 0; mt < 2; ++mt) O[mt] = MFMA16(aA[mt], uB, Op[mt]);
#pragma unroll
        for (int mt = 0; mt < 2; ++mt)
#pragma unroll
        for (int rg = 0; rg < 4; ++rg)
            out[(row0 + 16*mt + 4*quad + rg) * DV + c0 + ln15] = O[mt][rg];

        // (13b) prefetch attn/v/beta(ch+1)
        loadA(chn);
        loadVB(chn);
    }
}

// ---------------- Phase 2 (mid): round-1 scan (needs no kwT) ---------------

__global__ __launch_bounds__(64, 1)
void scan_kernel(const float* __restrict__ v, const float* __restrict__ beta,
                 const unsigned short* __restrict__ qw, const unsigned short* __restrict__ kw,
                 const unsigned short* __restrict__ Tw, const unsigned short* __restrict__ Aw,
                 float* __restrict__ out)
{
    const int id = blockIdx.x;
    const int bh = id & 31, cb = id >> 5, c0 = cb * 16;
    const int l = threadIdx.x;
    const int quad = (l >> 4) & 3, ln15 = l & 15, q8 = quad * 8;
    const int hi = l >> 5;

    __shared__ unsigned short knR[4392];
    __shared__ unsigned short Xt[16][40];
    __shared__ unsigned short ut[16][40];

    const f32x4 Z = {0.f, 0.f, 0.f, 0.f};
    f32x4 Sacc[8];
#pragma unroll
    for (int t = 0; t < 8; ++t) Sacc[t] = Z;

    const size_t bhL = (size_t)bh * L_SEQ;
    const int a0 = (((l & 16) << 1) | ln15) << 2;
    const int a1 = a0 + 64;

    bf16x8 kAa[2][4], kAb[2][4];
    bf16x8 qA[2][4], tA[2], aA[2], knA[8], uB;
    float vr[8], br[8];

    auto loadK = [&](int ch, bf16x8 (&kA)[2][4]){
        const unsigned short* kp = kw + (bhL + (size_t)ch * CHUNK) * DK;
#pragma unroll
        for (int mt = 0; mt < 2; ++mt)
#pragma unroll
        for (int ks = 0; ks < 4; ++ks)
            kA[mt][ks] = *(const bf16x8*)(kp + (16*mt + ln15) * DK + 32*ks + q8);
    };
    auto loadQ = [&](int ch){
        const unsigned short* qp = qw + (bhL + (size_t)ch * CHUNK) * DK;
#pragma unroll
        for (int mt = 0; mt < 2; ++mt)
#pragma unroll
        for (int ks = 0; ks < 4; ++ks)
            qA[mt][ks] = *(const bf16x8*)(qp + (16*mt + ln15) * DK + 32*ks + q8);
    };
    auto loadT = [&](int ch){
        const unsigned short* Tp = Tw + ((size_t)(bh * NCH + ch) << 10);
#pragma unroll
        for (int mt = 0; mt < 2; ++mt)
            tA[mt] = *(const bf16x8*)(Tp + (16*mt + ln15) * 32 + q8);
    };
    auto loadA = [&](int ch){
        const unsigned short* Ap = Aw + ((size_t)(bh * NCH + ch) << 10);
#pragma unroll
        for (int mt = 0; mt < 2; ++mt)
            aA[mt] = *(const bf16x8*)(Ap + (16*mt + ln15) * 32 + q8);
    };
    auto loadVB = [&](int ch){
        const size_t row0 = bhL + (size_t)ch * CHUNK;
#pragma unroll
        for (int g = 0; g < 8; ++g){
            int i = 16*(g >> 2) + 4*quad + (g & 3);
            vr[g] = v[(row0 + i) * DV + c0 + ln15];
            br[g] = beta[row0 + i];
        }
    };

    loadK(0, kAa);
    loadQ(0); loadT(0); loadA(0); loadVB(0);
    loadK(1, kAb);
    {
        U8 z; z.u[0] = 0u; z.u[1] = 0u; z.u[2] = 0u; z.u[3] = 0u;
        uB = z.v;
#pragma unroll
        for (int t = 0; t < 8; ++t) knA[t] = z.v;
    }

    auto body = [&](int ch, bf16x8 (&cur)[2][4]){
        const size_t row0 = bhL + (size_t)ch * CHUNK;

#pragma unroll
        for (int t = 0; t < 8; ++t)
            Sacc[t] = MFMA16(knA[t], uB, Sacc[t]);

        int P[8][2];
#pragma unroll
        for (int t = 0; t < 8; ++t){
            P[t][0] = (int)pk2(Sacc[t][0], Sacc[t][1]);
            P[t][1] = (int)pk2(Sacc[t][2], Sacc[t][3]);
        }
        bf16x8 SB[4];
#pragma unroll
        for (int ks = 0; ks < 4; ++ks){
            U8 sb;
            int e, f;
            e = __builtin_amdgcn_ds_bpermute(a0, P[2*ks][0]);
            f = __builtin_amdgcn_ds_bpermute(a0, P[2*ks+1][0]);
            sb.u[0] = (unsigned)(hi ? f : e);
            e = __builtin_amdgcn_ds_bpermute(a0, P[2*ks][1]);
            f = __builtin_amdgcn_ds_bpermute(a0, P[2*ks+1][1]);
            sb.u[1] = (unsigned)(hi ? f : e);
            e = __builtin_amdgcn_ds_bpermute(a1, P[2*ks][0]);
            f = __builtin_amdgcn_ds_bpermute(a1, P[2*ks+1][0]);
            sb.u[2] = (unsigned)(hi ? f : e);
            e = __builtin_amdgcn_ds_bpermute(a1, P[2*ks][1]);
            f = __builtin_amdgcn_ds_bpermute(a1, P[2*ks+1][1]);
            sb.u[3] = (unsigned)(hi ? f : e);
            SB[ks] = sb.v;
        }

        f32x4 Y[2] = {Z, Z}, Op[2] = {Z, Z};
#pragma unroll
        for (int ks = 0; ks < 4; ++ks)
#pragma unroll
        for (int mt = 0; mt < 2; ++mt){
            Y[mt]  = MFMA16(cur[mt][ks], SB[ks], Y[mt]);
            Op[mt] = MFMA16(qA[mt][ks],  SB[ks], Op[mt]);
        }

#pragma unroll
        for (int mt = 0; mt < 2; ++mt){
            unsigned int w0 = pk2(br[4*mt+0] * (vr[4*mt+0] - Y[mt][0]),
                                  br[4*mt+1] * (vr[4*mt+1] - Y[mt][1]));
            unsigned int w1 = pk2(br[4*mt+2] * (vr[4*mt+2] - Y[mt][2]),
                                  br[4*mt+3] * (vr[4*mt+3] - Y[mt][3]));
            *(unsigned int*)&Xt[ln15][16*mt + 4*quad]     = w0;
            *(unsigned int*)&Xt[ln15][16*mt + 4*quad + 2] = w1;
        }

#pragma unroll
        for (int mt = 0; mt < 2; ++mt)
#pragma unroll
        for (int ks = 0; ks < 4; ++ks){
            int i = 16*mt + ln15;
            int ad = i * 136 + (i >> 3) * 16 + 32*ks + q8;
            *(bf16x8*)&knR[ad] = cur[mt][ks];
        }

        bf16x8 Xb = *(const bf16x8*)&Xt[ln15][q8];

        unsigned int rja[32];
#pragma unroll
        for (int t = 0; t < 4; ++t)
#pragma unroll
        for (int j = 0; j < 8; ++j)
            rja[8*t + j] = knR[(q8 + j) * 136 + ((q8 + j) >> 3) * 16 + 16*t + ln15];

        f32x4 U[2];
#pragma unroll
        for (int mt = 0; mt < 2; ++mt) U[mt] = MFMA16(tA[mt], Xb, Z);

#pragma unroll
        for (int mt = 0; mt < 2; ++mt){
            *(unsigned int*)&ut[ln15][16*mt + 4*quad]     = pk2(U[mt][0], U[mt][1]);
            *(unsigned int*)&ut[ln15][16*mt + 4*quad + 2] = pk2(U[mt][2], U[mt][3]);
        }

#pragma unroll
        for (int t = 0; t < 4; ++t){
            U8 kk;
            kk.u[0] = rja[8*t+0] | (rja[8*t+1] << 16);
            kk.u[1] = rja[8*t+2] | (rja[8*t+3] << 16);
            kk.u[2] = rja[8*t+4] | (rja[8*t+5] << 16);
            kk.u[3] = rja[8*t+6] | (rja[8*t+7] << 16);
            knA[t] = kk.v;
        }

        uB = *(const bf16x8*)&ut[ln15][q8];

        const int chn = (ch + 1 < NCH) ? ch + 1 : NCH - 1;
        const int ch2 = (ch + 2 < NCH) ? ch + 2 : NCH - 1;
        loadQ(chn); loadT(chn); loadVB(chn);
        loadK(ch2, cur);

        unsigned int rjb[32];
#pragma unroll
        for (int t = 0; t < 4; ++t)
#pragma unroll
        for (int j = 0; j < 8; ++j)
            rjb[8*t + j] = knR[(q8 + j) * 136 + ((q8 + j) >> 3) * 16 + 16*(t + 4) + ln15];

        f32x4 O[2];
#pragma unroll
        for (int mt = 0; mt < 2; ++mt) O[mt] = MFMA16(aA[mt], uB, Op[mt]);
#pragma unroll
        for (int mt = 0; mt < 2; ++mt)
#pragma unroll
        for (int rg = 0; rg < 4; ++rg)
            out[(row0 + 16*mt + 4*quad + rg) * DV + c0 + ln15] = O[mt][rg];

#pragma unroll
        for (int t = 0; t < 4; ++t){
            U8 kk;
            kk.u[0] = rjb[8*t+0] | (rjb[8*t+1] << 16);
            kk.u[1] = rjb[8*t+2] | (rjb[8*t+3] << 16);
            kk.u[2] = rjb[8*t+4] | (rjb[8*t+5] << 16);
            kk.u[3] = rjb[8*t+6] | (rjb[8*t+7] << 16);
            knA[t + 4] = kk.v;
        }
        loadA(chn);
    };

    for (int ch = 0; ch < NCH; ch += 2){
        body(ch,     kAa);
        body(ch + 1, kAb);
    }
}

// ---------------- Fallback (round-1 fused kernel) if ws too small ----------

__global__ __launch_bounds__(512, 1)
void deltanet_fused(const float* __restrict__ q, const float* __restrict__ k,
                    const float* __restrict__ v, const float* __restrict__ beta,
                    float* __restrict__ out)
{
    const int bh = blockIdx.x;
    const int tid = threadIdx.x;
    const int n = L_SEQ / CHUNK;

    __shared__ float S[DK][DV + 1];
    __shared__ float qs[CHUNK][DK + 1];
    __shared__ float ks[CHUNK][DK + 1];
    __shared__ float vs[CHUNK][DV + 1];
    __shared__ float kbs[CHUNK][DK + 1];
    __shared__ float T[CHUNK][CHUNK + 1];
    __shared__ float at[CHUNK][CHUNK + 1];
    __shared__ float bet[CHUNK];

    for (int idx = tid; idx < DK * DV; idx += 512)
        S[idx / DV][idx % DV] = 0.f;
    __syncthreads();

    const size_t base_bh = (size_t)bh * L_SEQ;

    for (int ch = 0; ch < n; ++ch){
        const size_t row0 = base_bh + (size_t)ch * CHUNK;
        for (int idx = tid; idx < CHUNK * DK; idx += 512){
            int r = idx >> 7, c = idx & 127;
            size_t g = (row0 + (size_t)r) * DK + c;
            qs[r][c] = q[g]; ks[r][c] = k[g]; vs[r][c] = v[g];
        }
        if (tid < CHUNK) bet[tid] = beta[row0 + tid];
        __syncthreads();
        if (tid < 64){
            int r = tid & 31;
            const float* src = (tid < 32) ? &qs[r][0] : &ks[r][0];
            float s = 0.f;
            for (int d = 0; d < DK; ++d){ float x = src[d]; s += x * x; }
            at[(tid < 32) ? 0 : 1][r] = 1.0f / sqrtf(s + 1e-6f);
        }
        __syncthreads();
        for (int idx = tid; idx < CHUNK * DK; idx += 512){
            int r = idx >> 7, c = idx & 127;
            float qq = qs[r][c] * at[0][r];
            float kk = ks[r][c] * at[1][r];
            float b = bet[r];
            qs[r][c] = qq; ks[r][c] = kk; kbs[r][c] = kk * b; vs[r][c] *= b;
        }
        __syncthreads();
        for (int idx = tid; idx < CHUNK * CHUNK; idx += 512){
            int i = idx >> 5, j = idx & 31;
            float s = 0.f;
            if (j < i){
                for (int d = 0; d < DK; ++d) s += kbs[i][d] * ks[j][d];
                s = -s;
            }
            T[i][j] = s;
        }
        __syncthreads();
        for (int i = 1; i < CHUNK; ++i){
            float upd = 0.f;
            if (tid < i){
                int j = tid;
                for (int kk = j + 1; kk < i; ++kk) upd += T[i][kk] * T[kk][j];
            }
            __syncthreads();
            if (tid < i) T[i][tid] += upd;
            __syncthreads();
        }
        if (tid < CHUNK) T[tid][tid] = 1.0f;
        __syncthreads();
        {
            int c = tid & 127;
            int i0 = (tid >> 7) * 8;
            float uacc[8], wacc[8];
#pragma unroll
            for (int r = 0; r < 8; ++r){ uacc[r] = 0.f; wacc[r] = 0.f; }
            for (int j = 0; j < CHUNK; ++j){
                float vvv = vs[j][c], kb = kbs[j][c];
#pragma unroll
                for (int r = 0; r < 8; ++r){
                    float tt = T[i0 + r][j];
                    uacc[r] += tt * vvv; wacc[r] += tt * kb;
                }
            }
            __syncthreads();
#pragma unroll
            for (int r = 0; r < 8; ++r){ vs[i0 + r][c] = uacc[r]; kbs[i0 + r][c] = wacc[r]; }
        }
        __syncthreads();
        for (int idx = tid; idx < CHUNK * CHUNK; idx += 512){
            int i = idx >> 5, j = idx & 31;
            float s = 0.f;
            if (j <= i) for (int d = 0; d < DK; ++d) s += qs[i][d] * ks[j][d];
            at[i][j] = s;
        }
        __syncthreads();
        {
            int c = tid & 127;
            int i0 = (tid >> 7) * 8;
            float acc[8];
#pragma unroll
            for (int r = 0; r < 8; ++r) acc[r] = 0.f;
            for (int d = 0; d < DK; ++d){
                float sv = S[d][c];
#pragma unroll
                for (int r = 0; r < 8; ++r) acc[r] += kbs[i0 + r][d] * sv;
            }
#pragma unroll
            for (int r = 0; r < 8; ++r) vs[i0 + r][c] -= acc[r];
        }
        __syncthreads();
        {
            int c = tid & 127;
            int i0 = (tid >> 7) * 8;
            float acc[8];
#pragma unroll
            for (int r = 0; r < 8; ++r) acc[r] = 0.f;
            for (int d = 0; d < DK; ++d){
                float sv = S[d][c];
#pragma unroll
                for (int r = 0; r < 8; ++r) acc[r] += qs[i0 + r][d] * sv;
            }
            for (int j = 0; j < CHUNK; ++j){
                float uv = vs[j][c];
#pragma unroll
                for (int r = 0; r < 8; ++r) acc[r] += at[i0 + r][j] * uv;
            }
#pragma unroll
            for (int r = 0; r < 8; ++r)
                out[(row0 + (size_t)(i0 + r)) * DV + c] = acc[r];
        }
        __syncthreads();
        {
            int c = tid & 127;
            int d0 = (tid >> 7) * 32;
            float acc[32];
#pragma unroll
            for (int r = 0; r < 32; ++r) acc[r] = 0.f;
            for (int i = 0; i < CHUNK; ++i){
                float uv = vs[i][c];
#pragma unroll
                for (int r = 0; r < 32; ++r) acc[r] += ks[i][d0 + r] * uv;
            }
#pragma unroll
            for (int r = 0; r < 32; ++r) S[d0 + r][c] += acc[r];
        }
        __syncthreads();
    }
}

extern "C" void kernel_launch(void* const* d_in, const int* in_sizes, int n_in,
                              void* d_out, int out_size, void* d_ws, size_t ws_size,
                              hipStream_t stream) {
    const float* q = (const float*)d_in[0];
    const float* k = (const float*)d_in[1];
    const float* v = (const float*)d_in[2];
    const float* beta = (const float*)d_in[3];
    float* out = (float*)d_out;

    const size_t QK = (size_t)BH * L_SEQ * DK;       // 16,777,216 shorts
    const size_t TA = (size_t)BH * NCH * 1024;       //  4,194,304 shorts
    const size_t need_full = (3 * QK + 2 * TA) * sizeof(unsigned short); // ~117.4 MB
    const size_t need_mid  = (2 * QK + 2 * TA) * sizeof(unsigned short); // ~83.9 MB

    if (ws_size >= need_full){
        unsigned short* qwp = (unsigned short*)d_ws;
        unsigned short* kwp = qwp + QK;
        unsigned short* Twp = kwp + QK;
        unsigned short* Awp = Twp + TA;
        unsigned short* kTp = Awp + TA;
        prep_kernel<true><<<BH * NCH, 64, 0, stream>>>(q, k, beta, qwp, kwp, Twp, Awp, kTp);
        scan_fast<<<BH * 8, 64, 0, stream>>>(v, beta, qwp, kwp, kTp, Twp, Awp, out);
    } else if (ws_size >= need_mid){
        unsigned short* qwp = (unsigned short*)d_ws;
        unsigned short* kwp = qwp + QK;
        unsigned short* Twp = kwp + QK;
        unsigned short* Awp = Twp + TA;
        prep_kernel<false><<<BH * NCH, 64, 0, stream>>>(q, k, beta, qwp, kwp, Twp, Awp, nullptr);
        scan_kernel<<<BH * 8, 64, 0, stream>>>(v, beta, qwp, kwp, Twp, Awp, out);
    } else {
        deltanet_fused<<<BH, 512, 0, stream>>>(q, k, v, beta, out);
    }
}